// Round 1
// baseline (554.636 us; speedup 1.0000x reference)
//
#include <hip/hip_runtime.h>

#define PRE   1024
#define POST  1024
#define BATCH 256
#define HIST  50
#define NPAIR (PRE * POST)

// ---------------- kernel 1: batch means + EMA ----------------
__global__ __launch_bounds__(256) void means_kernel(
    const float* __restrict__ pre_spikes,   // [BATCH, PRE]
    const float* __restrict__ post_spikes,  // [BATCH, POST]
    const float* __restrict__ pre_activity, // [PRE]
    const float* __restrict__ post_activity,// [POST]
    float* __restrict__ ws_means,           // [PRE + POST] scratch
    float* __restrict__ out_pre_act,        // [PRE]
    float* __restrict__ out_post_act)       // [POST]
{
    int gid = blockIdx.x * blockDim.x + threadIdx.x;
    if (gid < PRE) {
        int j = gid;
        float s = 0.f;
        for (int b = 0; b < BATCH; ++b) s += pre_spikes[b * PRE + j];
        float m = s * (1.0f / BATCH);
        ws_means[j] = m;
        out_pre_act[j] = 0.99f * pre_activity[j] + 0.01f * m;
    } else if (gid < PRE + POST) {
        int j = gid - PRE;
        float s = 0.f;
        for (int b = 0; b < BATCH; ++b) s += post_spikes[b * POST + j];
        float m = s * (1.0f / BATCH);
        ws_means[PRE + j] = m;
        out_post_act[j] = 0.99f * post_activity[j] + 0.01f * m;
    }
}

// ---------------- kernel 2: masked SGEMM ----------------
// C[b][j] = sum_k A[b][k] * (W[k][j] * M[k][j])
#define BM 32
#define BN 32
#define BK 32
__global__ __launch_bounds__(256) void gemm_kernel(
    const float* __restrict__ A,   // [BATCH, PRE]
    const float* __restrict__ W,   // [PRE, POST]
    const float* __restrict__ Mk,  // [PRE, POST]
    float* __restrict__ C)         // [BATCH, POST]
{
    __shared__ float As[BM][BK + 1];
    __shared__ float Bs[BK][BN + 1];
    int tid = threadIdx.x;
    int bm = blockIdx.y;           // 0..BATCH/BM-1
    int bn = blockIdx.x;           // 0..POST/BN-1
    int tx = tid & 31;
    int ty = tid >> 5;             // 0..7
    float acc[4] = {0.f, 0.f, 0.f, 0.f};
    for (int k0 = 0; k0 < PRE; k0 += BK) {
#pragma unroll
        for (int q = 0; q < 4; ++q) {
            int l = q * 256 + tid;
            int r = l >> 5, c = l & 31;
            As[r][c] = A[(bm * BM + r) * PRE + k0 + c];
            int wi = (k0 + r) * POST + bn * BN + c;
            Bs[r][c] = W[wi] * Mk[wi];
        }
        __syncthreads();
#pragma unroll
        for (int kk = 0; kk < BK; ++kk) {
            float b = Bs[kk][tx];
#pragma unroll
            for (int m = 0; m < 4; ++m)
                acc[m] += As[ty + 8 * m][kk] * b;
        }
        __syncthreads();
    }
#pragma unroll
    for (int m = 0; m < 4; ++m)
        C[(bm * BM + ty + 8 * m) * POST + bn * BN + tx] = acc[m];
}

// ---------------- kernel 3: history copy+scatter + mean over HIST ----------------
// Each block: 256 pairs. 50 floats/pair = 25 float2/pair (a float2 never
// straddles a pair since pair stride 50 is even). Stage coalesced into LDS,
// write out with slot idx replaced, then per-thread pair-sum from LDS.
#define PPB 256
__global__ __launch_bounds__(256) void history_kernel(
    const float* __restrict__ hist_in,    // [PRE, POST, HIST]
    const int*   __restrict__ corr_index, // scalar
    const float* __restrict__ ws_means,   // [PRE + POST]
    float* __restrict__ hist_out,         // [PRE, POST, HIST]
    float* __restrict__ avg_out)          // [PRE, POST]
{
    __shared__ float tile[PPB * HIST];    // 51200 B
    int tid = threadIdx.x;
    int p0 = blockIdx.x * PPB;
    int idx = ((corr_index[0] % HIST) + HIST) % HIST;

    const float2* in2  = (const float2*)hist_in + (size_t)p0 * (HIST / 2);
    float2*       out2 = (float2*)hist_out + (size_t)p0 * (HIST / 2);
    float2*       tile2 = (float2*)tile;

#pragma unroll
    for (int it = 0; it < (PPB * HIST / 2) / 256; ++it) {   // 25 iters
        int fl = it * 256 + tid;                            // float2 idx in chunk
        float2 v = in2[fl];
        tile2[fl] = v;                                      // original values
        int t0 = (2 * fl) % HIST;                           // even
        if (t0 == idx || t0 + 1 == idx) {
            int pair = p0 + fl / (HIST / 2);
            float corr = ws_means[pair >> 10] * ws_means[PRE + (pair & (POST - 1))];
            if (t0 == idx) v.x = corr; else v.y = corr;
        }
        out2[fl] = v;
    }
    __syncthreads();

    int pair = p0 + tid;
    const float* tp = &tile[tid * HIST];
    float s = 0.f;
#pragma unroll
    for (int k = 0; k < HIST; ++k) s += tp[k];
    float corr = ws_means[pair >> 10] * ws_means[PRE + (pair & (POST - 1))];
    s = s - tp[idx] + corr;
    avg_out[pair] = s * (1.0f / HIST);
}

extern "C" void kernel_launch(void* const* d_in, const int* in_sizes, int n_in,
                              void* d_out, int out_size, void* d_ws, size_t ws_size,
                              hipStream_t stream)
{
    const float* pre_spikes  = (const float*)d_in[0];
    const float* post_spikes = (const float*)d_in[1];
    const float* W           = (const float*)d_in[2];
    const float* Mk          = (const float*)d_in[3];
    const float* hist        = (const float*)d_in[4];
    const float* pre_act     = (const float*)d_in[5];
    const float* post_act    = (const float*)d_in[6];
    const int*   corr_index  = (const int*)d_in[7];

    float* out = (float*)d_out;
    float* out_current  = out;                          // [256,1024]   262144
    float* out_pre_act  = out + 262144;                 // [1024]
    float* out_post_act = out + 263168;                 // [1024]
    float* out_avg      = out + 264192;                 // [1024,1024]  1048576
    float* out_hist     = out + 1312768;                // [1024,1024,50]

    float* ws_means = (float*)d_ws;                     // 2048 floats

    means_kernel<<<(PRE + POST) / 256, 256, 0, stream>>>(
        pre_spikes, post_spikes, pre_act, post_act,
        ws_means, out_pre_act, out_post_act);

    gemm_kernel<<<dim3(POST / BN, BATCH / BM), 256, 0, stream>>>(
        pre_spikes, W, Mk, out_current);

    history_kernel<<<NPAIR / PPB, 256, 0, stream>>>(
        hist, corr_index, ws_means, out_hist, out_avg);
}

// Round 2
// 464.386 us; speedup vs baseline: 1.1943x; 1.1943x over previous
//
#include <hip/hip_runtime.h>

#define PRE   1024
#define POST  1024
#define BATCH 256
#define HIST  50
#define NPAIR (PRE * POST)

// ---------------- kernel 1: batch means + EMA ----------------
// 64 columns per block, 4 row-chunks of 64 rows each, LDS reduce.
// blocks 0..15: pre, 16..31: post.
__global__ __launch_bounds__(256) void means_kernel(
    const float* __restrict__ pre_spikes,   // [BATCH, PRE]
    const float* __restrict__ post_spikes,  // [BATCH, POST]
    const float* __restrict__ pre_activity, // [PRE]
    const float* __restrict__ post_activity,// [POST]
    float* __restrict__ ws_means,           // [PRE + POST] scratch
    float* __restrict__ out_pre_act,        // [PRE]
    float* __restrict__ out_post_act)       // [POST]
{
    __shared__ float red[256];
    int tid = threadIdx.x;
    int blk = blockIdx.x;
    bool is_pre = blk < 16;
    const float* mat = is_pre ? pre_spikes : post_spikes;
    const float* act = is_pre ? pre_activity : post_activity;
    float* out_act   = is_pre ? out_pre_act : out_post_act;
    float* ws        = is_pre ? ws_means : ws_means + PRE;
    int col0 = (blk & 15) * 64;

    int col = col0 + (tid & 63);
    int chunk = tid >> 6;                  // 0..3
    float s = 0.f;
#pragma unroll 8
    for (int r = chunk * 64; r < chunk * 64 + 64; ++r)
        s += mat[r * 1024 + col];
    red[tid] = s;
    __syncthreads();
    if (tid < 64) {
        float t = red[tid] + red[tid + 64] + red[tid + 128] + red[tid + 192];
        float m = t * (1.0f / BATCH);
        ws[col] = m;
        out_act[col] = 0.99f * act[col] + 0.01f * m;
    }
}

// ---------------- kernel 2: masked SGEMM, split-K x4 ----------------
// C[b][j] += sum_{k in chunk} A[b][k] * (W[k][j]*M[k][j]); C pre-zeroed.
#define BM 32
#define BN 32
#define BK 32
#define KSPLIT 4
#define LDT 36   // padded LDS stride (float4-aligned, conflict-free col reads)
__global__ __launch_bounds__(256) void gemm_kernel(
    const float* __restrict__ A,   // [BATCH, PRE]
    const float* __restrict__ W,   // [PRE, POST]
    const float* __restrict__ Mk,  // [PRE, POST]
    float* __restrict__ C)         // [BATCH, POST]
{
    __shared__ __align__(16) float As[BM * LDT];
    __shared__ __align__(16) float Bs[BK * LDT];
    int tid = threadIdx.x;
    int bn = blockIdx.x, bm = blockIdx.y, bz = blockIdx.z;
    int tx = tid & 31;
    int ty = tid >> 5;                     // 0..7
    // staging coords: one float4 per thread per array
    int sr = tid >> 3;                     // row 0..31
    int sc = (tid & 7) * 4;                // col 0,4,..,28
    float acc[4] = {0.f, 0.f, 0.f, 0.f};
    int kbase = bz * (PRE / KSPLIT);

    for (int k0 = 0; k0 < PRE / KSPLIT; k0 += BK) {
        int kk0 = kbase + k0;
        float4 av = *(const float4*)&A[(bm * BM + sr) * PRE + kk0 + sc];
        const float* wrow = &W [(kk0 + sr) * POST + bn * BN + sc];
        const float* mrow = &Mk[(kk0 + sr) * POST + bn * BN + sc];
        float4 wv = *(const float4*)wrow;
        float4 mv = *(const float4*)mrow;
        wv.x *= mv.x; wv.y *= mv.y; wv.z *= mv.z; wv.w *= mv.w;
        *(float4*)&As[sr * LDT + sc] = av;
        *(float4*)&Bs[sr * LDT + sc] = wv;
        __syncthreads();
#pragma unroll
        for (int kk = 0; kk < BK; ++kk) {
            float b = Bs[kk * LDT + tx];
#pragma unroll
            for (int m = 0; m < 4; ++m)
                acc[m] += As[(ty + 8 * m) * LDT + kk] * b;
        }
        __syncthreads();
    }
#pragma unroll
    for (int m = 0; m < 4; ++m)
        atomicAdd(&C[(bm * BM + ty + 8 * m) * POST + bn * BN + tx], acc[m]);
}

// ---------------- kernel 3: history copy+scatter + mean over HIST ----------------
// 128 pairs/block. Phase 1: 7 independent float4 loads/thread staged into
// registers, then LDS + global writes (verbatim copy). Phase 2 (after
// barrier): per-pair sum from LDS, avg write, and a single scalar store
// overwriting slot idx with corr (ordered vs phase-1 stores by barrier).
#define PPB 128
#define BLK_F4 (PPB * HIST / 4)   // 1600 float4 per block
#define NIT 7                     // ceil(1600/256)
__global__ __launch_bounds__(256) void history_kernel(
    const float* __restrict__ hist_in,    // [PRE, POST, HIST]
    const int*   __restrict__ corr_index, // scalar
    const float* __restrict__ ws_means,   // [PRE + POST]
    float* __restrict__ hist_out,         // [PRE, POST, HIST]
    float* __restrict__ avg_out)          // [PRE, POST]
{
    __shared__ __align__(16) float tile[PPB * HIST];   // 25600 B
    int tid = threadIdx.x;
    int p0 = blockIdx.x * PPB;
    int idx = ((corr_index[0] % HIST) + HIST) % HIST;

    const float4* in4  = (const float4*)(hist_in + (size_t)p0 * HIST);
    float4*       out4 = (float4*)(hist_out + (size_t)p0 * HIST);
    float4*       tile4 = (float4*)tile;

    float4 v[NIT];
#pragma unroll
    for (int it = 0; it < NIT; ++it) {
        int fl = it * 256 + tid;
        if (fl < BLK_F4) v[it] = in4[fl];
    }
#pragma unroll
    for (int it = 0; it < NIT; ++it) {
        int fl = it * 256 + tid;
        if (fl < BLK_F4) {
            tile4[fl] = v[it];
            out4[fl]  = v[it];
        }
    }
    __syncthreads();

    if (tid < PPB) {
        int pair = p0 + tid;
        float corr = ws_means[pair >> 10] * ws_means[PRE + (pair & (POST - 1))];
        const float2* tp = (const float2*)&tile[tid * HIST];
        float s = 0.f;
#pragma unroll
        for (int k = 0; k < HIST / 2; ++k) {
            float2 w = tp[k];
            s += w.x + w.y;
        }
        s = s - tile[tid * HIST + idx] + corr;
        avg_out[pair] = s * (1.0f / HIST);
        hist_out[(size_t)pair * HIST + idx] = corr;   // scatter slot idx
    }
}

extern "C" void kernel_launch(void* const* d_in, const int* in_sizes, int n_in,
                              void* d_out, int out_size, void* d_ws, size_t ws_size,
                              hipStream_t stream)
{
    const float* pre_spikes  = (const float*)d_in[0];
    const float* post_spikes = (const float*)d_in[1];
    const float* W           = (const float*)d_in[2];
    const float* Mk          = (const float*)d_in[3];
    const float* hist        = (const float*)d_in[4];
    const float* pre_act     = (const float*)d_in[5];
    const float* post_act    = (const float*)d_in[6];
    const int*   corr_index  = (const int*)d_in[7];

    float* out = (float*)d_out;
    float* out_current  = out;                          // [256,1024]   262144
    float* out_pre_act  = out + 262144;                 // [1024]
    float* out_post_act = out + 263168;                 // [1024]
    float* out_avg      = out + 264192;                 // [1024,1024]  1048576
    float* out_hist     = out + 1312768;                // [1024,1024,50]

    float* ws_means = (float*)d_ws;                     // 2048 floats

    means_kernel<<<32, 256, 0, stream>>>(
        pre_spikes, post_spikes, pre_act, post_act,
        ws_means, out_pre_act, out_post_act);

    hipMemsetAsync(out_current, 0, (size_t)BATCH * POST * sizeof(float), stream);

    gemm_kernel<<<dim3(POST / BN, BATCH / BM, KSPLIT), 256, 0, stream>>>(
        pre_spikes, W, Mk, out_current);

    history_kernel<<<NPAIR / PPB, 256, 0, stream>>>(
        hist, corr_index, ws_means, out_hist, out_avg);
}

// Round 3
// 440.703 us; speedup vs baseline: 1.2585x; 1.0537x over previous
//
#include <hip/hip_runtime.h>

#define PRE   1024
#define POST  1024
#define BATCH 256
#define HIST  50
#define NPAIR (PRE * POST)

// ---------------- kernel 1: batch means + EMA ----------------
__global__ __launch_bounds__(256) void means_kernel(
    const float* __restrict__ pre_spikes,   // [BATCH, PRE]
    const float* __restrict__ post_spikes,  // [BATCH, POST]
    const float* __restrict__ pre_activity, // [PRE]
    const float* __restrict__ post_activity,// [POST]
    float* __restrict__ ws_means,           // [PRE + POST] scratch
    float* __restrict__ out_pre_act,        // [PRE]
    float* __restrict__ out_post_act)       // [POST]
{
    __shared__ float red[256];
    int tid = threadIdx.x;
    int blk = blockIdx.x;
    bool is_pre = blk < 16;
    const float* mat = is_pre ? pre_spikes : post_spikes;
    const float* act = is_pre ? pre_activity : post_activity;
    float* out_act   = is_pre ? out_pre_act : out_post_act;
    float* ws        = is_pre ? ws_means : ws_means + PRE;
    int col0 = (blk & 15) * 64;

    int col = col0 + (tid & 63);
    int chunk = tid >> 6;                  // 0..3
    float s = 0.f;
#pragma unroll 8
    for (int r = chunk * 64; r < chunk * 64 + 64; ++r)
        s += mat[r * 1024 + col];
    red[tid] = s;
    __syncthreads();
    if (tid < 64) {
        float t = red[tid] + red[tid + 64] + red[tid + 128] + red[tid + 192];
        float m = t * (1.0f / BATCH);
        ws[col] = m;
        out_act[col] = 0.99f * act[col] + 0.01f * m;
    }
}

// ---------------- kernel 2: masked SGEMM, split-K x4 ----------------
#define BM 32
#define BN 32
#define BK 32
#define KSPLIT 4
#define LDT 36
__global__ __launch_bounds__(256) void gemm_kernel(
    const float* __restrict__ A,   // [BATCH, PRE]
    const float* __restrict__ W,   // [PRE, POST]
    const float* __restrict__ Mk,  // [PRE, POST]
    float* __restrict__ C)         // [BATCH, POST]
{
    __shared__ __align__(16) float As[BM * LDT];
    __shared__ __align__(16) float Bs[BK * LDT];
    int tid = threadIdx.x;
    int bn = blockIdx.x, bm = blockIdx.y, bz = blockIdx.z;
    int tx = tid & 31;
    int ty = tid >> 5;
    int sr = tid >> 3;
    int sc = (tid & 7) * 4;
    float acc[4] = {0.f, 0.f, 0.f, 0.f};
    int kbase = bz * (PRE / KSPLIT);

    for (int k0 = 0; k0 < PRE / KSPLIT; k0 += BK) {
        int kk0 = kbase + k0;
        float4 av = *(const float4*)&A[(bm * BM + sr) * PRE + kk0 + sc];
        const float* wrow = &W [(kk0 + sr) * POST + bn * BN + sc];
        const float* mrow = &Mk[(kk0 + sr) * POST + bn * BN + sc];
        float4 wv = *(const float4*)wrow;
        float4 mv = *(const float4*)mrow;
        wv.x *= mv.x; wv.y *= mv.y; wv.z *= mv.z; wv.w *= mv.w;
        *(float4*)&As[sr * LDT + sc] = av;
        *(float4*)&Bs[sr * LDT + sc] = wv;
        __syncthreads();
#pragma unroll
        for (int kk = 0; kk < BK; ++kk) {
            float b = Bs[kk * LDT + tx];
#pragma unroll
            for (int m = 0; m < 4; ++m)
                acc[m] += As[(ty + 8 * m) * LDT + kk] * b;
        }
        __syncthreads();
    }
#pragma unroll
    for (int m = 0; m < 4; ++m)
        atomicAdd(&C[(bm * BM + ty + 8 * m) * POST + bn * BN + tx], acc[m]);
}

// ---------------- kernel 3: history copy + in-flight scatter + mean ----------------
// 128 pairs/block (6400 floats = 1600 float4), 320 threads -> exactly 5
// float4 loads/thread. Slot idx is substituted IN the copied vector before
// both the LDS and global stores (no post-hoc scalar store: R2 showed that
// costs +248 MB of HBM write RMW traffic). A float4 holds at most one
// slot-idx element; since 50 % 4 != 0 it may straddle two pairs -> two
// range checks, one div/mod per float4.
#define PPB 128
#define HTHREADS 320
#define NIT 5                      // 1600 / 320
__global__ __launch_bounds__(HTHREADS) void history_kernel(
    const float* __restrict__ hist_in,    // [PRE, POST, HIST]
    const int*   __restrict__ corr_index, // scalar
    const float* __restrict__ ws_means,   // [PRE + POST]
    float* __restrict__ hist_out,         // [PRE, POST, HIST]
    float* __restrict__ avg_out)          // [PRE, POST]
{
    __shared__ __align__(16) float tile[PPB * HIST];   // 25600 B
    int tid = threadIdx.x;
    int p0 = blockIdx.x * PPB;
    int idx = ((corr_index[0] % HIST) + HIST) % HIST;

    const float4* in4   = (const float4*)(hist_in + (size_t)p0 * HIST);
    float4*       out4  = (float4*)(hist_out + (size_t)p0 * HIST);
    float4*       tile4 = (float4*)tile;

    float4 v[NIT];
#pragma unroll
    for (int it = 0; it < NIT; ++it)
        v[it] = in4[it * HTHREADS + tid];

#pragma unroll
    for (int it = 0; it < NIT; ++it) {
        int fl = it * HTHREADS + tid;
        int r0 = 4 * fl;               // relative float index of component 0
        int pl = r0 / HIST;            // local pair of component 0
        int t0 = r0 - pl * HIST;       // slot of component 0
        int d  = idx - t0;             // component holding slot idx (same pair)
        int d2 = idx + HIST - t0;      // component holding slot idx (next pair)
        float* comps = (float*)&v[it];
        if (d >= 0 && d < 4) {
            int pair = p0 + pl;
            comps[d] = ws_means[pair >> 10] * ws_means[PRE + (pair & (POST - 1))];
        } else if (d2 < 4) {
            int pair = p0 + pl + 1;
            comps[d2] = ws_means[pair >> 10] * ws_means[PRE + (pair & (POST - 1))];
        }
        tile4[fl] = v[it];
        out4[fl]  = v[it];
    }
    __syncthreads();

    if (tid < PPB) {
        int pair = p0 + tid;
        const float2* tp = (const float2*)&tile[tid * HIST];
        float s = 0.f;
#pragma unroll
        for (int k = 0; k < HIST / 2; ++k) {
            float2 w = tp[k];
            s += w.x + w.y;
        }
        avg_out[pair] = s * (1.0f / HIST);
    }
}

extern "C" void kernel_launch(void* const* d_in, const int* in_sizes, int n_in,
                              void* d_out, int out_size, void* d_ws, size_t ws_size,
                              hipStream_t stream)
{
    const float* pre_spikes  = (const float*)d_in[0];
    const float* post_spikes = (const float*)d_in[1];
    const float* W           = (const float*)d_in[2];
    const float* Mk          = (const float*)d_in[3];
    const float* hist        = (const float*)d_in[4];
    const float* pre_act     = (const float*)d_in[5];
    const float* post_act    = (const float*)d_in[6];
    const int*   corr_index  = (const int*)d_in[7];

    float* out = (float*)d_out;
    float* out_current  = out;                          // [256,1024]   262144
    float* out_pre_act  = out + 262144;                 // [1024]
    float* out_post_act = out + 263168;                 // [1024]
    float* out_avg      = out + 264192;                 // [1024,1024]  1048576
    float* out_hist     = out + 1312768;                // [1024,1024,50]

    float* ws_means = (float*)d_ws;                     // 2048 floats

    means_kernel<<<32, 256, 0, stream>>>(
        pre_spikes, post_spikes, pre_act, post_act,
        ws_means, out_pre_act, out_post_act);

    hipMemsetAsync(out_current, 0, (size_t)BATCH * POST * sizeof(float), stream);

    gemm_kernel<<<dim3(POST / BN, BATCH / BM, KSPLIT), 256, 0, stream>>>(
        pre_spikes, W, Mk, out_current);

    history_kernel<<<NPAIR / PPB, HTHREADS, 0, stream>>>(
        hist, corr_index, ws_means, out_hist, out_avg);
}